// Round 1
// baseline (538.825 us; speedup 1.0000x reference)
//
#include <hip/hip_runtime.h>
#include <hip/hip_bf16.h>

// Problem: B=2, S=4096, H=768, NH=12, DH=64. fp32 in/out, bf16 MFMA compute.
#define B_ 2
#define S_ 4096
#define H_ 768
#define NH_ 12
#define DH_ 64
#define M_ (B_ * S_)   // 8192 rows of x
#define N3_ (3 * H_)   // 2304 fused QKV cols
#define K_ H_          // 768

typedef __attribute__((ext_vector_type(8))) short short8;   // 8 bf16 (4 VGPR) MFMA A/B frag
typedef __attribute__((ext_vector_type(4))) float f32x4;    // MFMA C/D frag
typedef __attribute__((ext_vector_type(4))) unsigned int uint4v;

__device__ __forceinline__ unsigned short f2bf(float f) {
    unsigned int u = __builtin_bit_cast(unsigned int, f);
    u += 0x7FFFu + ((u >> 16) & 1u);   // RNE
    return (unsigned short)(u >> 16);
}

// ---------------- cast x: fp32 -> bf16, vectorized ----------------
__global__ __launch_bounds__(256) void cast_x_kernel(const float* __restrict__ x,
                                                     unsigned short* __restrict__ xb) {
    int i = blockIdx.x * 256 + threadIdx.x;   // grid sized exactly: n/4 threads
    float4 v = reinterpret_cast<const float4*>(x)[i];
    ushort4 o;
    o.x = f2bf(v.x); o.y = f2bf(v.y); o.z = f2bf(v.z); o.w = f2bf(v.w);
    reinterpret_cast<ushort4*>(xb)[i] = o;
}

// ------- cast+transpose W: Wt[(wsel*768+n)*768 + k] = W_wsel[k*768+n] -------
__global__ __launch_bounds__(256) void cast_w_kernel(const float* __restrict__ Wq,
                                                     const float* __restrict__ Wk,
                                                     const float* __restrict__ Wv,
                                                     unsigned short* __restrict__ wt) {
    int idx = blockIdx.x * 256 + threadIdx.x;   // total 3*768*768, exact grid
    int k = idx % H_;
    int nn = idx / H_;
    int n = nn % H_;
    int wsel = nn / H_;
    const float* W = (wsel == 0) ? Wq : (wsel == 1) ? Wk : Wv;
    wt[idx] = f2bf(W[k * H_ + n]);
}

// ---------------- fused QKV GEMM: [8192x768] @ [768x2304] + bias ----------------
// 128x128 tile, BK=32, 4 waves (2x2), each wave 64x64 via 4x4 frags of 16x16x32.
#define BM 128
#define BN 128
#define BK 32
#define LDT 40   // LDS row stride (bf16 elems): 80B -> 2-way bank alias only (free)

__global__ __launch_bounds__(256) void qkv_gemm_kernel(const unsigned short* __restrict__ xb,
                                                       const unsigned short* __restrict__ wt,
                                                       const float* __restrict__ bq,
                                                       const float* __restrict__ bk,
                                                       const float* __restrict__ bv,
                                                       unsigned short* __restrict__ qkv) {
    __shared__ unsigned short Asm[BM * LDT];
    __shared__ unsigned short Bsm[BN * LDT];
    const int tid = threadIdx.x;
    const int nTiles = N3_ / BN;            // 18
    const int bm = blockIdx.x / nTiles;
    const int bn = blockIdx.x % nTiles;
    const int w = tid >> 6, l = tid & 63;
    const int wm = w >> 1, wn = w & 1;
    const int lr = l & 15, lk = l >> 4;

    f32x4 zero = {0.f, 0.f, 0.f, 0.f};
    f32x4 acc[4][4];
#pragma unroll
    for (int i = 0; i < 4; i++)
#pragma unroll
        for (int j = 0; j < 4; j++) acc[i][j] = zero;

    const int srow = tid >> 2;          // 0..63 (+64 for second half)
    const int scol = (tid & 3) * 8;     // 0,8,16,24
    const unsigned short* aG = xb + (size_t)(bm * BM + srow) * K_ + scol;
    const unsigned short* bG = wt + (size_t)(bn * BN + srow) * K_ + scol;

    for (int k0 = 0; k0 < K_; k0 += BK) {
        __syncthreads();   // protect LDS from previous iteration's readers
        *reinterpret_cast<uint4v*>(&Asm[srow * LDT + scol]) =
            *reinterpret_cast<const uint4v*>(aG + k0);
        *reinterpret_cast<uint4v*>(&Asm[(srow + 64) * LDT + scol]) =
            *reinterpret_cast<const uint4v*>(aG + (size_t)64 * K_ + k0);
        *reinterpret_cast<uint4v*>(&Bsm[srow * LDT + scol]) =
            *reinterpret_cast<const uint4v*>(bG + k0);
        *reinterpret_cast<uint4v*>(&Bsm[(srow + 64) * LDT + scol]) =
            *reinterpret_cast<const uint4v*>(bG + (size_t)64 * K_ + k0);
        __syncthreads();

        short8 a[4], b[4];
#pragma unroll
        for (int mi = 0; mi < 4; mi++)
            a[mi] = *reinterpret_cast<const short8*>(&Asm[(wm * 64 + mi * 16 + lr) * LDT + lk * 8]);
#pragma unroll
        for (int ni = 0; ni < 4; ni++)
            b[ni] = *reinterpret_cast<const short8*>(&Bsm[(wn * 64 + ni * 16 + lr) * LDT + lk * 8]);
#pragma unroll
        for (int mi = 0; mi < 4; mi++)
#pragma unroll
            for (int ni = 0; ni < 4; ni++)
                acc[mi][ni] = __builtin_amdgcn_mfma_f32_16x16x32_bf16(a[mi], b[ni], acc[mi][ni], 0, 0, 0);
    }

    // epilogue: bias + bf16 store. C/D layout: col = lane&15, row = (lane>>4)*4 + i
#pragma unroll
    for (int ni = 0; ni < 4; ni++) {
        const int col = bn * BN + wn * 64 + ni * 16 + lr;
        const float bias = (col < H_) ? bq[col] : (col < 2 * H_) ? bk[col - H_] : bv[col - 2 * H_];
#pragma unroll
        for (int mi = 0; mi < 4; mi++) {
#pragma unroll
            for (int i = 0; i < 4; i++) {
                const int row = bm * BM + wm * 64 + mi * 16 + lk * 4 + i;
                qkv[(size_t)row * N3_ + col] = f2bf(acc[mi][ni][i] + bias);
            }
        }
    }
}

// ---------------- flash attention fwd + tanh ----------------
// Block: 4 waves, each owns 16 q-rows (QBLK=64). KBLK=64 keys/tile.
// K in LDS [key][d] stride 72 (2-way banks). V in LDS transposed [d][key] with
// XOR swizzle on the 8-key block index (block' = block ^ (d>>4)) to break the
// staging write conflict. P per-wave through LDS (wave-local: lgkmcnt fence only).
#define QBLK 64
#define KBLK 64
#define LDK 72

__global__ __launch_bounds__(256) void attn_kernel(const unsigned short* __restrict__ qkv,
                                                   float* __restrict__ out) {
    __shared__ unsigned short Ksm[KBLK * LDK];       // [key][d]
    __shared__ unsigned short Vsm[DH_ * LDK];        // [d][key-swizzled]
    __shared__ unsigned short Psm[4 * 16 * LDK];     // per-wave [16 q][64 key]

    const int tid = threadIdx.x;
    const int w = tid >> 6, l = tid & 63;
    const int lr = l & 15, lk = l >> 4;
    const int qt = blockIdx.x & (S_ / QBLK - 1);     // 64 q-tiles
    const int bh = blockIdx.x >> 6;
    const int b = bh / NH_, h = bh % NH_;

    const unsigned short* Qb = qkv + (size_t)b * S_ * N3_ + h * DH_;
    const unsigned short* Kb = Qb + H_;
    const unsigned short* Vb = Qb + 2 * H_;

    // Q frags live in registers for the whole kernel. A-frag: row=lane&15, k=(lane>>4)*8+j
    const int qrow = qt * QBLK + w * 16 + lr;
    const short8 aq0 = *reinterpret_cast<const short8*>(Qb + (size_t)qrow * N3_ + lk * 8);
    const short8 aq1 = *reinterpret_cast<const short8*>(Qb + (size_t)qrow * N3_ + 32 + lk * 8);

    f32x4 zero = {0.f, 0.f, 0.f, 0.f};
    f32x4 acc[4];
#pragma unroll
    for (int dn = 0; dn < 4; dn++) acc[dn] = zero;
    float m_[4], lsum[4];
#pragma unroll
    for (int i = 0; i < 4; i++) { m_[i] = -INFINITY; lsum[i] = 0.f; }

    // staging map: 4 threads per key row, 16 d each (2x 16B loads)
    const int skey = tid >> 2;
    const int sd0 = (tid & 3) * 16;
    const int vcol = ((((skey >> 3) ^ (tid & 3)) << 3) | (skey & 7));  // swizzled key col

    for (int kt = 0; kt < S_; kt += KBLK) {
        __syncthreads();   // all waves done reading previous K/V tile
        const unsigned short* kg = Kb + (size_t)(kt + skey) * N3_;
        *reinterpret_cast<uint4v*>(&Ksm[skey * LDK + sd0]) =
            *reinterpret_cast<const uint4v*>(kg + sd0);
        *reinterpret_cast<uint4v*>(&Ksm[skey * LDK + sd0 + 8]) =
            *reinterpret_cast<const uint4v*>(kg + sd0 + 8);
        const unsigned short* vg = Vb + (size_t)(kt + skey) * N3_;
        short8 v0 = *reinterpret_cast<const short8*>(vg + sd0);
        short8 v1 = *reinterpret_cast<const short8*>(vg + sd0 + 8);
#pragma unroll
        for (int j = 0; j < 8; j++)
            Vsm[(sd0 + j) * LDK + vcol] = (unsigned short)v0[j];
#pragma unroll
        for (int j = 0; j < 8; j++)
            Vsm[(sd0 + 8 + j) * LDK + vcol] = (unsigned short)v1[j];
        __syncthreads();

        // ---- S = (Q K^T) * 1/8 ----
        f32x4 s[4];
#pragma unroll
        for (int kn = 0; kn < 4; kn++) {
            short8 bk0 = *reinterpret_cast<const short8*>(&Ksm[(kn * 16 + lr) * LDK + lk * 8]);
            short8 bk1 = *reinterpret_cast<const short8*>(&Ksm[(kn * 16 + lr) * LDK + 32 + lk * 8]);
            f32x4 z = zero;
            z = __builtin_amdgcn_mfma_f32_16x16x32_bf16(aq0, bk0, z, 0, 0, 0);
            s[kn] = __builtin_amdgcn_mfma_f32_16x16x32_bf16(aq1, bk1, z, 0, 0, 0);
        }
#pragma unroll
        for (int kn = 0; kn < 4; kn++)
#pragma unroll
            for (int i = 0; i < 4; i++) s[kn][i] *= 0.125f;

        // ---- online softmax (rows live in 16-lane groups; reduce over lane&15) ----
        float mnew[4], corr[4], rs[4];
#pragma unroll
        for (int i = 0; i < 4; i++) {
            float t = fmaxf(fmaxf(s[0][i], s[1][i]), fmaxf(s[2][i], s[3][i]));
#pragma unroll
            for (int off = 1; off < 16; off <<= 1) t = fmaxf(t, __shfl_xor(t, off));
            mnew[i] = fmaxf(m_[i], t);
            corr[i] = __expf(m_[i] - mnew[i]);
            m_[i] = mnew[i];
            rs[i] = 0.f;
        }
#pragma unroll
        for (int kn = 0; kn < 4; kn++) {
#pragma unroll
            for (int i = 0; i < 4; i++) {
                float p = __expf(s[kn][i] - mnew[i]);
                rs[i] += p;
                Psm[(w * 16 + lk * 4 + i) * LDK + kn * 16 + lr] = f2bf(p);
            }
        }
#pragma unroll
        for (int i = 0; i < 4; i++) {
            float r = rs[i];
#pragma unroll
            for (int off = 1; off < 16; off <<= 1) r += __shfl_xor(r, off);
            lsum[i] = lsum[i] * corr[i] + r;
        }
#pragma unroll
        for (int dn = 0; dn < 4; dn++)
#pragma unroll
            for (int i = 0; i < 4; i++) acc[dn][i] *= corr[i];

        // P writes are wave-local: drain LDS queue, then read back as A-frags.
        asm volatile("s_waitcnt lgkmcnt(0)" ::: "memory");
        short8 ap0 = *reinterpret_cast<const short8*>(&Psm[(w * 16 + lr) * LDK + lk * 8]);
        short8 ap1 = *reinterpret_cast<const short8*>(&Psm[(w * 16 + lr) * LDK + 32 + lk * 8]);
#pragma unroll
        for (int dn = 0; dn < 4; dn++) {
            const int d0 = dn * 16 + lr;
            short8 bv0 = *reinterpret_cast<const short8*>(&Vsm[d0 * LDK + ((lk ^ dn) << 3)]);
            short8 bv1 = *reinterpret_cast<const short8*>(&Vsm[d0 * LDK + (((4 + lk) ^ dn) << 3)]);
            acc[dn] = __builtin_amdgcn_mfma_f32_16x16x32_bf16(ap0, bv0, acc[dn], 0, 0, 0);
            acc[dn] = __builtin_amdgcn_mfma_f32_16x16x32_bf16(ap1, bv1, acc[dn], 0, 0, 0);
        }
    }

    // epilogue: normalize, tanh, fp32 store
#pragma unroll
    for (int dn = 0; dn < 4; dn++) {
#pragma unroll
        for (int i = 0; i < 4; i++) {
            const int q = qt * QBLK + w * 16 + lk * 4 + i;
            out[(size_t)(b * S_ + q) * H_ + h * DH_ + dn * 16 + lr] =
                tanhf(acc[dn][i] / lsum[i]);
        }
    }
}

extern "C" void kernel_launch(void* const* d_in, const int* in_sizes, int n_in,
                              void* d_out, int out_size, void* d_ws, size_t ws_size,
                              hipStream_t stream) {
    const float* x  = (const float*)d_in[0];
    const float* Wq = (const float*)d_in[1];
    const float* bq = (const float*)d_in[2];
    const float* Wk = (const float*)d_in[3];
    const float* bk = (const float*)d_in[4];
    const float* Wv = (const float*)d_in[5];
    const float* bv = (const float*)d_in[6];
    float* out = (float*)d_out;

    // workspace layout (bytes): xb 12.6MB | wt 3.5MB | qkv 37.7MB  (~53.9MB total)
    char* ws = (char*)d_ws;
    unsigned short* xb  = (unsigned short*)ws;
    size_t off = (size_t)M_ * K_ * 2;
    unsigned short* wt  = (unsigned short*)(ws + off);
    off += (size_t)N3_ * K_ * 2;
    unsigned short* qkv = (unsigned short*)(ws + off);

    cast_x_kernel<<<dim3((M_ * K_) / 4 / 256), dim3(256), 0, stream>>>(x, xb);
    cast_w_kernel<<<dim3((3 * H_ * H_) / 256), dim3(256), 0, stream>>>(Wq, Wk, Wv, wt);
    qkv_gemm_kernel<<<dim3((M_ / BM) * (N3_ / BN)), dim3(256), 0, stream>>>(xb, wt, bq, bk, bv, qkv);
    attn_kernel<<<dim3(B_ * NH_ * (S_ / QBLK)), dim3(256), 0, stream>>>(qkv, out);
}

// Round 4
// 321.839 us; speedup vs baseline: 1.6742x; 1.6742x over previous
//
#include <hip/hip_runtime.h>
#include <hip/hip_bf16.h>

// B=2, S=4096, H=768, NH=12, DH=64. fp32 in/out, bf16 MFMA compute.
#define B_ 2
#define S_ 4096
#define H_ 768
#define NH_ 12
#define DH_ 64
#define M_ (B_ * S_)    // 8192
#define N3_ (3 * H_)    // 2304
#define NQK 1536        // Q,K interleaved row width
#define K_ H_
#define LOG2E 1.4426950408889634f

typedef __attribute__((ext_vector_type(8))) short short8;     // 8 bf16 (4 VGPR)
typedef __attribute__((ext_vector_type(4))) float f32x4;
typedef __attribute__((ext_vector_type(16))) float f32x16;
typedef __attribute__((ext_vector_type(4))) unsigned int uint4v;
typedef __attribute__((ext_vector_type(4))) unsigned short ushort4v;

__device__ __forceinline__ unsigned short f2bf(float f) {
    unsigned int u = __builtin_bit_cast(unsigned int, f);
    u += 0x7FFFu + ((u >> 16) & 1u);   // RNE
    return (unsigned short)(u >> 16);
}
__device__ __forceinline__ unsigned int cvtpk_bf16(float lo, float hi) {
    unsigned int r;
    asm("v_cvt_pk_bf16_f32 %0, %1, %2" : "=v"(r) : "v"(lo), "v"(hi));
    return r;
}
// post: x.hi32lanes <- y.lo32lanes(lane^32), y.lo32lanes <- x.hi32lanes(lane^32)
__device__ __forceinline__ void plswap32(unsigned int &x, unsigned int &y) {
    asm("v_permlane32_swap_b32 %0, %1" : "+v"(x), "+v"(y));
}
__device__ __forceinline__ float exp2_fast(float x) {   // v_exp_f32: D = 2^S0
    float r;
    asm("v_exp_f32 %0, %1" : "=v"(r) : "v"(x));
    return r;
}

// ------- cast+transpose W: wt[(wsel*768+n)*768 + k] = W_wsel[k*768+n] -------
__global__ __launch_bounds__(256) void cast_w_kernel(const float* __restrict__ Wq,
                                                     const float* __restrict__ Wk,
                                                     const float* __restrict__ Wv,
                                                     unsigned short* __restrict__ wt) {
    int idx = blockIdx.x * 256 + threadIdx.x;
    int k = idx % H_;
    int nn = idx / H_;
    int n = nn % H_;
    int wsel = nn / H_;
    const float* W = (wsel == 0) ? Wq : (wsel == 1) ? Wk : Wv;
    wt[idx] = f2bf(W[k * H_ + n]);
}

// ---------------- fused QKV GEMM ----------------
// [8192x768]fp32 @ [768x2304]bf16 + bias. 128x128 tile, BK=32, 4 waves (2x2).
// Q,K cols -> qk[row][1536] bf16; V cols -> vT[(b*12+h)*64+d][s] bf16 (pre-transposed).
#define BM 128
#define BN 128
#define BK 32
#define LDT 40   // LDS row stride: 80B -> 2-way bank alias (free)

__global__ __launch_bounds__(256) void qkv_gemm_kernel(const float* __restrict__ x,
                                                       const unsigned short* __restrict__ wt,
                                                       const float* __restrict__ bq,
                                                       const float* __restrict__ bk,
                                                       const float* __restrict__ bv,
                                                       unsigned short* __restrict__ qk,
                                                       unsigned short* __restrict__ vT) {
    __shared__ unsigned short Asm[BM * LDT];
    __shared__ unsigned short Bsm[BN * LDT];
    const int tid = threadIdx.x;
    const int nTiles = N3_ / BN;            // 18
    const int bm = blockIdx.x / nTiles;
    const int bn = blockIdx.x % nTiles;
    const int w = tid >> 6, l = tid & 63;
    const int wm = w >> 1, wn = w & 1;
    const int lr = l & 15, lk = l >> 4;

    f32x4 zero = {0.f, 0.f, 0.f, 0.f};
    f32x4 acc[4][4];
#pragma unroll
    for (int i = 0; i < 4; i++)
#pragma unroll
        for (int j = 0; j < 4; j++) acc[i][j] = zero;

    const int srow = tid >> 2;          // 0..63 (+64 second half)
    const int scol = (tid & 3) * 8;     // 0,8,16,24
    const float* aG = x + (size_t)(bm * BM + srow) * K_ + scol;
    const unsigned short* bG = wt + (size_t)(bn * BN + srow) * K_ + scol;

    for (int k0 = 0; k0 < K_; k0 += BK) {
        __syncthreads();
        // A: fp32 -> bf16 on the fly
#pragma unroll
        for (int half = 0; half < 2; half++) {
            float4 a0 = *reinterpret_cast<const float4*>(aG + (size_t)half * 64 * K_ + k0);
            float4 a1 = *reinterpret_cast<const float4*>(aG + (size_t)half * 64 * K_ + k0 + 4);
            union { unsigned short s[8]; uint4v v; } u;
            u.s[0] = f2bf(a0.x); u.s[1] = f2bf(a0.y); u.s[2] = f2bf(a0.z); u.s[3] = f2bf(a0.w);
            u.s[4] = f2bf(a1.x); u.s[5] = f2bf(a1.y); u.s[6] = f2bf(a1.z); u.s[7] = f2bf(a1.w);
            *reinterpret_cast<uint4v*>(&Asm[(srow + half * 64) * LDT + scol]) = u.v;
        }
        *reinterpret_cast<uint4v*>(&Bsm[srow * LDT + scol]) =
            *reinterpret_cast<const uint4v*>(bG + k0);
        *reinterpret_cast<uint4v*>(&Bsm[(srow + 64) * LDT + scol]) =
            *reinterpret_cast<const uint4v*>(bG + (size_t)64 * K_ + k0);
        __syncthreads();

        short8 a[4], b[4];
#pragma unroll
        for (int mi = 0; mi < 4; mi++)
            a[mi] = *reinterpret_cast<const short8*>(&Asm[(wm * 64 + mi * 16 + lr) * LDT + lk * 8]);
#pragma unroll
        for (int ni = 0; ni < 4; ni++)
            b[ni] = *reinterpret_cast<const short8*>(&Bsm[(wn * 64 + ni * 16 + lr) * LDT + lk * 8]);
#pragma unroll
        for (int mi = 0; mi < 4; mi++)
#pragma unroll
            for (int ni = 0; ni < 4; ni++)
                acc[mi][ni] = __builtin_amdgcn_mfma_f32_16x16x32_bf16(a[mi], b[ni], acc[mi][ni], 0, 0, 0);
    }

    // epilogue. C/D: col = lane&15, row = (lane>>4)*4 + i
    if (bn < 12) {      // Q,K region -> qk[row][1536]
#pragma unroll
        for (int ni = 0; ni < 4; ni++) {
            const int col = bn * BN + wn * 64 + ni * 16 + lr;
            const float bias = (col < H_) ? bq[col] : bk[col - H_];
#pragma unroll
            for (int mi = 0; mi < 4; mi++) {
#pragma unroll
                for (int i = 0; i < 4; i++) {
                    const int row = bm * BM + wm * 64 + mi * 16 + lk * 4 + i;
                    qk[(size_t)row * NQK + col] = f2bf(acc[mi][ni][i] + bias);
                }
            }
        }
    } else {            // V region -> vT[(b*12+h)*64+d][s], 4 consecutive s packed
#pragma unroll
        for (int ni = 0; ni < 4; ni++) {
            const int c = bn * BN - 2 * H_ + wn * 64 + ni * 16 + lr;  // 0..767
            const int h = c >> 6, d = c & 63;
            const float bias = bv[c];
#pragma unroll
            for (int mi = 0; mi < 4; mi++) {
                const int row0 = bm * BM + wm * 64 + mi * 16 + lk * 4;
                const int b = row0 >> 12, s0 = row0 & (S_ - 1);
                union { unsigned short s[4]; ushort4v v; } u;
#pragma unroll
                for (int i = 0; i < 4; i++) u.s[i] = f2bf(acc[mi][ni][i] + bias);
                *reinterpret_cast<ushort4v*>(vT + ((size_t)(b * NH_ + h) * DH_ + d) * S_ + s0) = u.v;
            }
        }
    }
}

// ---------------- flash attention fwd + tanh ----------------
// 4 waves x 32 q-rows (QB=128), KB=64 keys/tile, 32x32x16 MFMA, swapped QK^T.
// K LDS [key][64] and V^T LDS [d][64], both XOR-swizzled (idx ^= (row&7)<<3).
// Softmax fully in-register (lane owns q=lane&31); P->A-frags via cvt_pk+permlane32_swap.
#define QW 32
#define QB 128
#define KB 64

__global__ __launch_bounds__(256, 2) void attn_kernel(const unsigned short* __restrict__ qk,
                                                      const unsigned short* __restrict__ vT,
                                                      float* __restrict__ out) {
    __shared__ unsigned short Ksm[KB * 64];
    __shared__ unsigned short Vsm[DH_ * KB];
    const int tid = threadIdx.x;
    const int w = tid >> 6, l = tid & 63;
    const int ln = l & 31, hi = l >> 5;
    // XCD-chunked swizzle: 768 blocks = 8 XCD x 96; co-locate same-head blocks.
    const int swz = (blockIdx.x & 7) * 96 + (blockIdx.x >> 3);
    const int qt = swz & 31, bh = swz >> 5;
    const int b = bh / NH_, h = bh % NH_;

    const unsigned short* Qg = qk + (size_t)b * S_ * NQK + h * DH_;
    const unsigned short* Kg = Qg + H_;
    const unsigned short* Vg = vT + (size_t)bh * DH_ * S_;

    // Q fragments in regs (B operand of swapped QK^T: lane ln = q row)
    const int qrow = qt * QB + w * QW + ln;
    short8 qf[4];
    {
        const unsigned short* qp = Qg + (size_t)qrow * NQK + hi * 8;
#pragma unroll
        for (int dk = 0; dk < 4; dk++)
            qf[dk] = *reinterpret_cast<const short8*>(qp + dk * 16);
    }

    const f32x16 fz = {0,0,0,0,0,0,0,0,0,0,0,0,0,0,0,0};
    f32x16 o0 = fz, o1 = fz;
    float m_ = -INFINITY, lsum = 0.f;
    const float SCL = 0.125f * LOG2E;   // score scale folded into exp2 domain

    // staging: thread -> (row = tid>>2, 16 elems at (tid&3)*16); 2x b128 each of K,V^T
    const int srow = tid >> 2;
    const int sd = (tid & 3) * 16;
    const unsigned short* kgp = Kg + (size_t)srow * NQK + sd;
    const unsigned short* vgp = Vg + (size_t)srow * S_ + sd;
    const int sidx0 = (srow * 64 + sd) ^ ((srow & 7) << 3);
    const int sidx1 = (srow * 64 + sd + 8) ^ ((srow & 7) << 3);

    for (int kt = 0; kt < S_; kt += KB) {
        __syncthreads();
        *reinterpret_cast<uint4v*>(&Ksm[sidx0]) = *reinterpret_cast<const uint4v*>(kgp + (size_t)kt * NQK);
        *reinterpret_cast<uint4v*>(&Ksm[sidx1]) = *reinterpret_cast<const uint4v*>(kgp + (size_t)kt * NQK + 8);
        *reinterpret_cast<uint4v*>(&Vsm[sidx0]) = *reinterpret_cast<const uint4v*>(vgp + kt);
        *reinterpret_cast<uint4v*>(&Vsm[sidx1]) = *reinterpret_cast<const uint4v*>(vgp + kt + 8);
        __syncthreads();

        // S^T = K Q^T : lane holds S[k=crow(r,hi)(+32)][q=ln], scaled into exp2 domain after
        f32x16 s0 = fz, s1 = fz;
#pragma unroll
        for (int dk = 0; dk < 4; dk++) {
            const int col = dk * 16 + hi * 8;
            short8 kf0 = *reinterpret_cast<const short8*>(&Ksm[(ln * 64 + col) ^ ((ln & 7) << 3)]);
            short8 kf1 = *reinterpret_cast<const short8*>(&Ksm[((32 + ln) * 64 + col) ^ ((ln & 7) << 3)]);
            s0 = __builtin_amdgcn_mfma_f32_32x32x16_bf16(kf0, qf[dk], s0, 0, 0, 0);
            s1 = __builtin_amdgcn_mfma_f32_32x32x16_bf16(kf1, qf[dk], s1, 0, 0, 0);
        }
#pragma unroll
        for (int r = 0; r < 16; r++) { s0[r] *= SCL; s1[r] *= SCL; }

        // ---- online softmax, in-register; defer-max (THR=8) ----
        float pmax = s0[0];
#pragma unroll
        for (int r = 1; r < 16; r++) pmax = fmaxf(pmax, s0[r]);
#pragma unroll
        for (int r = 0; r < 16; r++) pmax = fmaxf(pmax, s1[r]);
        pmax = fmaxf(pmax, __shfl_xor(pmax, 32));
        if (!__all(pmax - m_ <= 8.0f)) {
            const float mnew = fmaxf(m_, pmax);
            const float corr = exp2_fast(m_ - mnew);
            m_ = mnew;
            lsum *= corr;
#pragma unroll
            for (int r = 0; r < 16; r++) {
                const float c = __shfl(corr, (r & 3) + 8 * (r >> 2) + 4 * hi);
                o0[r] *= c; o1[r] *= c;
            }
        }
        float p[32];
        float rs = 0.f;
#pragma unroll
        for (int r = 0; r < 16; r++) { p[r] = exp2_fast(s0[r] - m_); rs += p[r]; }
#pragma unroll
        for (int r = 0; r < 16; r++) { p[16 + r] = exp2_fast(s1[r] - m_); rs += p[16 + r]; }
        rs += __shfl_xor(rs, 32);
        lsum += rs;

        // ---- P -> bf16 A-frags (T12: cvt_pk + permlane32_swap) ----
        short8 pa[4];
#pragma unroll
        for (int half = 0; half < 2; half++) {
            unsigned int c0 = cvtpk_bf16(p[half*16+0],  p[half*16+1]);
            unsigned int c1 = cvtpk_bf16(p[half*16+2],  p[half*16+3]);
            unsigned int c2 = cvtpk_bf16(p[half*16+4],  p[half*16+5]);
            unsigned int c3 = cvtpk_bf16(p[half*16+6],  p[half*16+7]);
            unsigned int c4 = cvtpk_bf16(p[half*16+8],  p[half*16+9]);
            unsigned int c5 = cvtpk_bf16(p[half*16+10], p[half*16+11]);
            unsigned int c6 = cvtpk_bf16(p[half*16+12], p[half*16+13]);
            unsigned int c7 = cvtpk_bf16(p[half*16+14], p[half*16+15]);
            plswap32(c0, c2); plswap32(c1, c3);   // slice 0: words {c0,c1,c2,c3}
            plswap32(c4, c6); plswap32(c5, c7);   // slice 1: words {c4,c5,c6,c7}
            union { unsigned int u[4]; short8 v; } ua, ub;
            ua.u[0] = c0; ua.u[1] = c1; ua.u[2] = c2; ua.u[3] = c3;
            ub.u[0] = c4; ub.u[1] = c5; ub.u[2] = c6; ub.u[3] = c7;
            pa[half * 2]     = ua.v;
            pa[half * 2 + 1] = ub.v;
        }

        // ---- O += P V : A=pa (m=q), B=V^T rows (n=d) ----
#pragma unroll
        for (int s4 = 0; s4 < 4; s4++) {
            const int kcol = s4 * 16 + hi * 8;
            short8 vf0 = *reinterpret_cast<const short8*>(&Vsm[(ln * 64 + kcol) ^ ((ln & 7) << 3)]);
            short8 vf1 = *reinterpret_cast<const short8*>(&Vsm[((32 + ln) * 64 + kcol) ^ ((ln & 7) << 3)]);
            o0 = __builtin_amdgcn_mfma_f32_32x32x16_bf16(pa[s4], vf0, o0, 0, 0, 0);
            o1 = __builtin_amdgcn_mfma_f32_32x32x16_bf16(pa[s4], vf1, o1, 0, 0, 0);
        }
    }

    // epilogue: O[q=crow(r,hi)][d=dt*32+ln], normalize, tanh, fp32 store
    float* op = out + ((size_t)b * S_ + qt * QB + w * QW) * H_ + h * DH_;
#pragma unroll
    for (int r = 0; r < 16; r++) {
        const int q = (r & 3) + 8 * (r >> 2) + 4 * hi;
        const float inv = 1.0f / __shfl(lsum, q);
        op[(size_t)q * H_ + ln]      = tanhf(o0[r] * inv);
        op[(size_t)q * H_ + 32 + ln] = tanhf(o1[r] * inv);
    }
}

extern "C" void kernel_launch(void* const* d_in, const int* in_sizes, int n_in,
                              void* d_out, int out_size, void* d_ws, size_t ws_size,
                              hipStream_t stream) {
    const float* x  = (const float*)d_in[0];
    const float* Wq = (const float*)d_in[1];
    const float* bq = (const float*)d_in[2];
    const float* Wk = (const float*)d_in[3];
    const float* bk = (const float*)d_in[4];
    const float* Wv = (const float*)d_in[5];
    const float* bv = (const float*)d_in[6];
    float* out = (float*)d_out;

    // ws layout (bytes): wt 3.54MB | qk 25.17MB | vT 12.58MB = 41.3MB total (< R1's proven 53.9MB)
    char* ws = (char*)d_ws;
    unsigned short* wt = (unsigned short*)ws;
    size_t off = (size_t)N3_ * K_ * 2;
    unsigned short* qkb = (unsigned short*)(ws + off);
    off += (size_t)M_ * NQK * 2;
    unsigned short* vTb = (unsigned short*)(ws + off);

    cast_w_kernel<<<dim3((3 * H_ * H_) / 256), dim3(256), 0, stream>>>(Wq, Wk, Wv, wt);
    qkv_gemm_kernel<<<dim3((M_ / BM) * (N3_ / BN)), dim3(256), 0, stream>>>(x, wt, bq, bk, bv, qkb, vTb);
    attn_kernel<<<dim3(B_ * NH_ * (S_ / QB)), dim3(256), 0, stream>>>(qkb, vTb, out);
}

// Round 5
// 284.303 us; speedup vs baseline: 1.8952x; 1.1320x over previous
//
#include <hip/hip_runtime.h>
#include <hip/hip_bf16.h>

// B=2, S=4096, H=768, NH=12, DH=64. fp32 in/out, bf16 MFMA compute.
#define B_ 2
#define S_ 4096
#define H_ 768
#define NH_ 12
#define DH_ 64
#define M_ (B_ * S_)    // 8192
#define N3_ (3 * H_)    // 2304
#define NQK 1536        // Q,K interleaved row width
#define K_ H_
#define LOG2E 1.4426950408889634f

typedef __attribute__((ext_vector_type(8))) short short8;     // 8 bf16 (4 VGPR)
typedef __attribute__((ext_vector_type(4))) float f32x4;
typedef __attribute__((ext_vector_type(16))) float f32x16;
typedef __attribute__((ext_vector_type(4))) unsigned int uint4v;
typedef __attribute__((ext_vector_type(4))) unsigned short ushort4v;

typedef __attribute__((address_space(3))) unsigned int lds_u32;
typedef const __attribute__((address_space(1))) unsigned int glb_u32;

__device__ __forceinline__ unsigned short f2bf(float f) {
    unsigned int u = __builtin_bit_cast(unsigned int, f);
    u += 0x7FFFu + ((u >> 16) & 1u);   // RNE
    return (unsigned short)(u >> 16);
}
__device__ __forceinline__ unsigned int cvtpk_bf16(float lo, float hi) {
    unsigned int r;
    asm("v_cvt_pk_bf16_f32 %0, %1, %2" : "=v"(r) : "v"(lo), "v"(hi));
    return r;
}
// post: x.hi32lanes <- y.lo32lanes(lane^32), y.lo32lanes <- x.hi32lanes(lane^32)
__device__ __forceinline__ void plswap32(unsigned int &x, unsigned int &y) {
    asm("v_permlane32_swap_b32 %0, %1" : "+v"(x), "+v"(y));
}
__device__ __forceinline__ float exp2_fast(float x) {   // v_exp_f32: D = 2^S0
    float r;
    asm("v_exp_f32 %0, %1" : "=v"(r) : "v"(x));
    return r;
}

// ---------------- cast x: fp32 -> bf16, vectorized ----------------
__global__ __launch_bounds__(256) void cast_x_kernel(const float* __restrict__ x,
                                                     unsigned short* __restrict__ xb) {
    int i = blockIdx.x * 256 + threadIdx.x;   // exact grid: n/4 threads
    float4 v = reinterpret_cast<const float4*>(x)[i];
    ushort4 o;
    o.x = f2bf(v.x); o.y = f2bf(v.y); o.z = f2bf(v.z); o.w = f2bf(v.w);
    reinterpret_cast<ushort4*>(xb)[i] = o;
}

// ------- cast+transpose W: wt[(wsel*768+n)*768+k] = W[k*768+n] -------
// Coalesced reads (wave spans 64 consecutive n), 16B/lane scattered writes.
__global__ __launch_bounds__(256) void cast_w_kernel(const float* __restrict__ Wq,
                                                     const float* __restrict__ Wk,
                                                     const float* __restrict__ Wv,
                                                     unsigned short* __restrict__ wt) {
    int id = blockIdx.x * 256 + threadIdx.x;   // 3*768*96 threads
    int n = id % H_;
    int kb = (id / H_) % 96;
    int wsel = id / (H_ * 96);
    const float* W = (wsel == 0) ? Wq : (wsel == 1) ? Wk : Wv;
    union { unsigned short s[8]; uint4v v; } u;
#pragma unroll
    for (int j = 0; j < 8; j++) u.s[j] = f2bf(W[(size_t)(kb * 8 + j) * H_ + n]);
    *reinterpret_cast<uint4v*>(wt + (size_t)(wsel * H_ + n) * H_ + kb * 8) = u.v;
}

// ---------------- fused QKV GEMM (m97 structure) ----------------
// [8192x768]bf16 @ [768x2304]bf16 + bias. 128x128 tile, BK=64, 4 waves (2x2),
// global_load_lds width-16 staging, linear LDS. Q epilogue pre-scales by 0.125*log2e.
#define GBM 128
#define GBN 128
#define GBK 64

__global__ __launch_bounds__(256) void qkv_gemm_kernel(const unsigned short* __restrict__ xb,
                                                       const unsigned short* __restrict__ wt,
                                                       const float* __restrict__ bq,
                                                       const float* __restrict__ bk,
                                                       const float* __restrict__ bv,
                                                       unsigned short* __restrict__ qk,
                                                       unsigned short* __restrict__ vT) {
    __shared__ unsigned short Asm[GBM * GBK];   // 16 KB
    __shared__ unsigned short Bsm[GBN * GBK];   // 16 KB
    const int tid = threadIdx.x;
    // chunked XCD swizzle: 1152 blocks = 8 x 144 (bijective)
    const int swz = (blockIdx.x & 7) * 144 + (blockIdx.x >> 3);
    const int bm = swz / 18, bn = swz % 18;
    const int w = tid >> 6, l = tid & 63;
    const int wm = w >> 1, wn = w & 1;
    const int lr = l & 15, lk = l >> 4;

    f32x4 zero = {0.f, 0.f, 0.f, 0.f};
    f32x4 acc[4][4];
#pragma unroll
    for (int i = 0; i < 4; i++)
#pragma unroll
        for (int j = 0; j < 4; j++) acc[i][j] = zero;

    // staging map: instr j = w*4+i covers rows j*8..j*8+7; lane: row j*8+(l>>3), col (l&7)*8
    const int srow = l >> 3;
    const int scol = (l & 7) * 8;
    const unsigned short* aBase = xb + (size_t)(bm * GBM) * K_;
    const unsigned short* bBase = wt + (size_t)(bn * GBN) * K_;

    for (int k0 = 0; k0 < K_; k0 += GBK) {
        __syncthreads();
#pragma unroll
        for (int i = 0; i < 4; i++) {
            const int j = w * 4 + i;
            __builtin_amdgcn_global_load_lds(
                (glb_u32*)(aBase + (size_t)(j * 8 + srow) * K_ + k0 + scol),
                (lds_u32*)(&Asm[j * 8 * GBK]), 16, 0, 0);
        }
#pragma unroll
        for (int i = 0; i < 4; i++) {
            const int j = w * 4 + i;
            __builtin_amdgcn_global_load_lds(
                (glb_u32*)(bBase + (size_t)(j * 8 + srow) * K_ + k0 + scol),
                (lds_u32*)(&Bsm[j * 8 * GBK]), 16, 0, 0);
        }
        __syncthreads();   // drains vmcnt -> LDS valid

#pragma unroll
        for (int ks = 0; ks < 2; ks++) {
            short8 a[4], b[4];
#pragma unroll
            for (int mi = 0; mi < 4; mi++)
                a[mi] = *reinterpret_cast<const short8*>(&Asm[(wm * 64 + mi * 16 + lr) * GBK + ks * 32 + lk * 8]);
#pragma unroll
            for (int ni = 0; ni < 4; ni++)
                b[ni] = *reinterpret_cast<const short8*>(&Bsm[(wn * 64 + ni * 16 + lr) * GBK + ks * 32 + lk * 8]);
#pragma unroll
            for (int mi = 0; mi < 4; mi++)
#pragma unroll
                for (int ni = 0; ni < 4; ni++)
                    acc[mi][ni] = __builtin_amdgcn_mfma_f32_16x16x32_bf16(a[mi], b[ni], acc[mi][ni], 0, 0, 0);
        }
    }

    // epilogue. C/D: col = lane&15, row = (lane>>4)*4 + i
    if (bn < 12) {      // Q,K region -> qk[row][1536]; Q pre-scaled in fp32
#pragma unroll
        for (int ni = 0; ni < 4; ni++) {
            const int col = bn * GBN + wn * 64 + ni * 16 + lr;
            const bool isQ = (col < H_);
            const float bias = isQ ? bq[col] : bk[col - H_];
            const float scl = isQ ? (0.125f * LOG2E) : 1.0f;
#pragma unroll
            for (int mi = 0; mi < 4; mi++) {
#pragma unroll
                for (int i = 0; i < 4; i++) {
                    const int row = bm * GBM + wm * 64 + mi * 16 + lk * 4 + i;
                    qk[(size_t)row * NQK + col] = f2bf((acc[mi][ni][i] + bias) * scl);
                }
            }
        }
    } else {            // V region -> vT[(b*12+h)*64+d][s], 4 consecutive s packed
#pragma unroll
        for (int ni = 0; ni < 4; ni++) {
            const int c = bn * GBN - 2 * H_ + wn * 64 + ni * 16 + lr;  // 0..767
            const int h = c >> 6, d = c & 63;
            const float bias = bv[c];
#pragma unroll
            for (int mi = 0; mi < 4; mi++) {
                const int row0 = bm * GBM + wm * 64 + mi * 16 + lk * 4;
                const int b = row0 >> 12, s0 = row0 & (S_ - 1);
                union { unsigned short s[4]; ushort4v v; } u;
#pragma unroll
                for (int i = 0; i < 4; i++) u.s[i] = f2bf(acc[mi][ni][i] + bias);
                *reinterpret_cast<ushort4v*>(vT + ((size_t)(b * NH_ + h) * DH_ + d) * S_ + s0) = u.v;
            }
        }
    }
}

// ---------------- flash attention fwd + tanh ----------------
// 4 waves x 32 q-rows (QB=128), KB=64, 32x32x16 MFMA, swapped QK^T, in-register
// softmax (Q pre-scaled into exp2 domain), T12 cvt_pk+permlane, T13 defer-max,
// T14 async-STAGE (raw s_barrier; no vmcnt drain at barriers).
#define QW 32
#define QB 128
#define KB 64

__global__ __launch_bounds__(256, 2) void attn_kernel(const unsigned short* __restrict__ qk,
                                                      const unsigned short* __restrict__ vT,
                                                      float* __restrict__ out) {
    __shared__ unsigned short Ksm[KB * 64];
    __shared__ unsigned short Vsm[DH_ * KB];
    const int tid = threadIdx.x;
    const int w = tid >> 6, l = tid & 63;
    const int ln = l & 31, hi = l >> 5;
    // XCD-chunked swizzle: 768 blocks = 8 XCD x 96
    const int swz = (blockIdx.x & 7) * 96 + (blockIdx.x >> 3);
    const int qt = swz & 31, bh = swz >> 5;
    const int b = bh / NH_, h = bh % NH_;

    const unsigned short* Qg = qk + (size_t)b * S_ * NQK + h * DH_;
    const unsigned short* Kg = Qg + H_;
    const unsigned short* Vg = vT + (size_t)bh * DH_ * S_;

    // Q fragments in regs (B operand of swapped QK^T: lane ln = q row)
    const int qrow = qt * QB + w * QW + ln;
    short8 qf[4];
    {
        const unsigned short* qp = Qg + (size_t)qrow * NQK + hi * 8;
#pragma unroll
        for (int dk = 0; dk < 4; dk++)
            qf[dk] = *reinterpret_cast<const short8*>(qp + dk * 16);
    }

    const f32x16 fz = {0,0,0,0,0,0,0,0,0,0,0,0,0,0,0,0};
    f32x16 o0 = fz, o1 = fz;
    float m_ = -INFINITY, lsum = 0.f;

    // staging: thread -> (row = tid>>2, 16 elems at (tid&3)*16); 2x 16B each of K,V^T
    const int srow = tid >> 2;
    const int sd = (tid & 3) * 16;
    const unsigned short* kgp = Kg + (size_t)srow * NQK + sd;
    const unsigned short* vgp = Vg + (size_t)srow * S_ + sd;
    const int sidx0 = (srow * 64 + sd) ^ ((srow & 7) << 3);
    const int sidx1 = (srow * 64 + sd + 8) ^ ((srow & 7) << 3);

    // T14: issue tile-0 loads before the loop
    uint4v kr0 = *reinterpret_cast<const uint4v*>(kgp);
    uint4v kr1 = *reinterpret_cast<const uint4v*>(kgp + 8);
    uint4v vr0 = *reinterpret_cast<const uint4v*>(vgp);
    uint4v vr1 = *reinterpret_cast<const uint4v*>(vgp + 8);

    for (int kt = 0; kt < S_; kt += KB) {
        // barrier 1: previous tile's readers done (no vmcnt drain!)
        asm volatile("" ::: "memory");
        __builtin_amdgcn_s_barrier();
        asm volatile("" ::: "memory");
        *reinterpret_cast<uint4v*>(&Ksm[sidx0]) = kr0;
        *reinterpret_cast<uint4v*>(&Ksm[sidx1]) = kr1;
        *reinterpret_cast<uint4v*>(&Vsm[sidx0]) = vr0;
        *reinterpret_cast<uint4v*>(&Vsm[sidx1]) = vr1;
        if (kt + KB < S_) {    // issue next-tile loads; they fly during compute
            kr0 = *reinterpret_cast<const uint4v*>(kgp + (size_t)(kt + KB) * NQK);
            kr1 = *reinterpret_cast<const uint4v*>(kgp + (size_t)(kt + KB) * NQK + 8);
            vr0 = *reinterpret_cast<const uint4v*>(vgp + kt + KB);
            vr1 = *reinterpret_cast<const uint4v*>(vgp + kt + KB + 8);
        }
        // barrier 2: LDS writes visible (lgkm only, vmcnt stays in flight)
        asm volatile("s_waitcnt lgkmcnt(0)" ::: "memory");
        __builtin_amdgcn_s_barrier();
        asm volatile("" ::: "memory");

        // S^T = K Q^T (already in exp2 domain: Q pre-scaled by 0.125*log2e)
        f32x16 s0 = fz, s1 = fz;
#pragma unroll
        for (int dk = 0; dk < 4; dk++) {
            const int col = dk * 16 + hi * 8;
            short8 kf0 = *reinterpret_cast<const short8*>(&Ksm[(ln * 64 + col) ^ ((ln & 7) << 3)]);
            short8 kf1 = *reinterpret_cast<const short8*>(&Ksm[((32 + ln) * 64 + col) ^ ((ln & 7) << 3)]);
            s0 = __builtin_amdgcn_mfma_f32_32x32x16_bf16(kf0, qf[dk], s0, 0, 0, 0);
            s1 = __builtin_amdgcn_mfma_f32_32x32x16_bf16(kf1, qf[dk], s1, 0, 0, 0);
        }

        // ---- online softmax, in-register; defer-max (THR=8) ----
        float pmax = fmaxf(fmaxf(s0[0], s0[1]), fmaxf(s0[2], s0[3]));
#pragma unroll
        for (int r = 4; r < 16; r += 4)
            pmax = fmaxf(pmax, fmaxf(fmaxf(s0[r], s0[r+1]), fmaxf(s0[r+2], s0[r+3])));
#pragma unroll
        for (int r = 0; r < 16; r += 4)
            pmax = fmaxf(pmax, fmaxf(fmaxf(s1[r], s1[r+1]), fmaxf(s1[r+2], s1[r+3])));
        pmax = fmaxf(pmax, __shfl_xor(pmax, 32));
        if (!__all(pmax - m_ <= 8.0f)) {
            const float mnew = fmaxf(m_, pmax);
            const float corr = exp2_fast(m_ - mnew);
            m_ = mnew;
            lsum *= corr;
#pragma unroll
            for (int r = 0; r < 16; r++) {
                const float c = __shfl(corr, (r & 3) + 8 * (r >> 2) + 4 * hi);
                o0[r] *= c; o1[r] *= c;
            }
        }
        float p[32];
        float rs = 0.f;
#pragma unroll
        for (int r = 0; r < 16; r++) { p[r] = exp2_fast(s0[r] - m_); rs += p[r]; }
#pragma unroll
        for (int r = 0; r < 16; r++) { p[16 + r] = exp2_fast(s1[r] - m_); rs += p[16 + r]; }
        rs += __shfl_xor(rs, 32);
        lsum += rs;

        // ---- P -> bf16 A-frags (T12: cvt_pk + permlane32_swap) ----
        short8 pa[4];
#pragma unroll
        for (int half = 0; half < 2; half++) {
            unsigned int c0 = cvtpk_bf16(p[half*16+0],  p[half*16+1]);
            unsigned int c1 = cvtpk_bf16(p[half*16+2],  p[half*16+3]);
            unsigned int c2 = cvtpk_bf16(p[half*16+4],  p[half*16+5]);
            unsigned int c3 = cvtpk_bf16(p[half*16+6],  p[half*16+7]);
            unsigned int c4 = cvtpk_bf16(p[half*16+8],  p[half*16+9]);
            unsigned int c5 = cvtpk_bf16(p[half*16+10], p[half*16+11]);
            unsigned int c6 = cvtpk_bf16(p[half*16+12], p[half*16+13]);
            unsigned int c7 = cvtpk_bf16(p[half*16+14], p[half*16+15]);
            plswap32(c0, c2); plswap32(c1, c3);
            plswap32(c4, c6); plswap32(c5, c7);
            union { unsigned int u[4]; short8 v; } ua, ub;
            ua.u[0] = c0; ua.u[1] = c1; ua.u[2] = c2; ua.u[3] = c3;
            ub.u[0] = c4; ub.u[1] = c5; ub.u[2] = c6; ub.u[3] = c7;
            pa[half * 2]     = ua.v;
            pa[half * 2 + 1] = ub.v;
        }

        // ---- O += P V : A=pa (m=q), B=V^T rows (n=d) ----
#pragma unroll
        for (int s4 = 0; s4 < 4; s4++) {
            const int kcol = s4 * 16 + hi * 8;
            short8 vf0 = *reinterpret_cast<const short8*>(&Vsm[(ln * 64 + kcol) ^ ((ln & 7) << 3)]);
            short8 vf1 = *reinterpret_cast<const short8*>(&Vsm[((32 + ln) * 64 + kcol) ^ ((ln & 7) << 3)]);
            o0 = __builtin_amdgcn_mfma_f32_32x32x16_bf16(pa[s4], vf0, o0, 0, 0, 0);
            o1 = __builtin_amdgcn_mfma_f32_32x32x16_bf16(pa[s4], vf1, o1, 0, 0, 0);
        }
    }

    // epilogue: O[q=crow(r,hi)][d=dt*32+ln], normalize, tanh, fp32 store
    float* op = out + ((size_t)b * S_ + qt * QB + w * QW) * H_ + h * DH_;
#pragma unroll
    for (int r = 0; r < 16; r++) {
        const int q = (r & 3) + 8 * (r >> 2) + 4 * hi;
        const float inv = 1.0f / __shfl(lsum, q);
        op[(size_t)q * H_ + ln]      = tanhf(o0[r] * inv);
        op[(size_t)q * H_ + 32 + ln] = tanhf(o1[r] * inv);
    }
}

extern "C" void kernel_launch(void* const* d_in, const int* in_sizes, int n_in,
                              void* d_out, int out_size, void* d_ws, size_t ws_size,
                              hipStream_t stream) {
    const float* x  = (const float*)d_in[0];
    const float* Wq = (const float*)d_in[1];
    const float* bq = (const float*)d_in[2];
    const float* Wk = (const float*)d_in[3];
    const float* bk = (const float*)d_in[4];
    const float* Wv = (const float*)d_in[5];
    const float* bv = (const float*)d_in[6];
    float* out = (float*)d_out;

    // ws (bytes): xb 12.58MB | wt 3.54MB | qk 25.17MB | vT 12.58MB = 53.87MB (= R1 proven budget)
    char* ws = (char*)d_ws;
    unsigned short* xb = (unsigned short*)ws;
    size_t off = (size_t)M_ * K_ * 2;
    unsigned short* wt = (unsigned short*)(ws + off);
    off += (size_t)N3_ * K_ * 2;
    unsigned short* qkb = (unsigned short*)(ws + off);
    off += (size_t)M_ * NQK * 2;
    unsigned short* vTb = (unsigned short*)(ws + off);

    cast_x_kernel<<<dim3((M_ * K_) / 4 / 256), dim3(256), 0, stream>>>(x, xb);
    cast_w_kernel<<<dim3((3 * H_ * 96) / 256), dim3(256), 0, stream>>>(Wq, Wk, Wv, wt);
    qkv_gemm_kernel<<<dim3((M_ / GBM) * (N3_ / GBN)), dim3(256), 0, stream>>>(xb, wt, bq, bk, bv, qkb, vTb);
    attn_kernel<<<dim3(B_ * NH_ * (S_ / QB)), dim3(256), 0, stream>>>(qkb, vTb, out);
}

// Round 6
// 270.842 us; speedup vs baseline: 1.9894x; 1.0497x over previous
//
#include <hip/hip_runtime.h>
#include <hip/hip_bf16.h>

// B=2, S=4096, H=768, NH=12, DH=64. fp32 in/out, bf16 MFMA compute.
#define B_ 2
#define S_ 4096
#define H_ 768
#define NH_ 12
#define DH_ 64
#define M_ (B_ * S_)    // 8192
#define N3_ (3 * H_)    // 2304
#define NQK 1536        // Q,K interleaved row width
#define K_ H_
#define LOG2E 1.4426950408889634f

typedef __attribute__((ext_vector_type(8))) short short8;     // 8 bf16 (4 VGPR)
typedef __attribute__((ext_vector_type(4))) float f32x4;
typedef __attribute__((ext_vector_type(16))) float f32x16;
typedef __attribute__((ext_vector_type(4))) unsigned int uint4v;
typedef __attribute__((ext_vector_type(4))) unsigned short ushort4v;

typedef __attribute__((address_space(3))) unsigned int lds_u32;
typedef const __attribute__((address_space(1))) unsigned int glb_u32;

__device__ __forceinline__ unsigned short f2bf(float f) {
    unsigned int u = __builtin_bit_cast(unsigned int, f);
    u += 0x7FFFu + ((u >> 16) & 1u);   // RNE
    return (unsigned short)(u >> 16);
}
__device__ __forceinline__ unsigned int cvtpk_bf16(float lo, float hi) {
    unsigned int r;
    asm("v_cvt_pk_bf16_f32 %0, %1, %2" : "=v"(r) : "v"(lo), "v"(hi));
    return r;
}
// post: x.hi32lanes <- y.lo32lanes(lane^32), y.lo32lanes <- x.hi32lanes(lane^32)
__device__ __forceinline__ void plswap32(unsigned int &x, unsigned int &y) {
    asm("v_permlane32_swap_b32 %0, %1" : "+v"(x), "+v"(y));
}
__device__ __forceinline__ float exp2_fast(float x) {   // v_exp_f32: D = 2^S0
    float r;
    asm("v_exp_f32 %0, %1" : "=v"(r) : "v"(x));
    return r;
}

// ---------------- cast x: fp32 -> bf16, vectorized ----------------
__global__ __launch_bounds__(256) void cast_x_kernel(const float* __restrict__ x,
                                                     unsigned short* __restrict__ xb) {
    int i = blockIdx.x * 256 + threadIdx.x;   // exact grid: n/4 threads
    float4 v = reinterpret_cast<const float4*>(x)[i];
    ushort4 o;
    o.x = f2bf(v.x); o.y = f2bf(v.y); o.z = f2bf(v.z); o.w = f2bf(v.w);
    reinterpret_cast<ushort4*>(xb)[i] = o;
}

// ------- cast+transpose W: wt[(wsel*768+n)*768+k] = W[k*768+n] -------
__global__ __launch_bounds__(256) void cast_w_kernel(const float* __restrict__ Wq,
                                                     const float* __restrict__ Wk,
                                                     const float* __restrict__ Wv,
                                                     unsigned short* __restrict__ wt) {
    int id = blockIdx.x * 256 + threadIdx.x;   // 3*768*96 threads
    int n = id % H_;
    int kb = (id / H_) % 96;
    int wsel = id / (H_ * 96);
    const float* W = (wsel == 0) ? Wq : (wsel == 1) ? Wk : Wv;
    union { unsigned short s[8]; uint4v v; } u;
#pragma unroll
    for (int j = 0; j < 8; j++) u.s[j] = f2bf(W[(size_t)(kb * 8 + j) * H_ + n]);
    *reinterpret_cast<uint4v*>(wt + (size_t)(wsel * H_ + n) * H_ + kb * 8) = u.v;
}

// ---------------- fused QKV GEMM (m97 structure + T2 both-sides swizzle) ----------------
// [8192x768]bf16 @ [768x2304]bf16 + bias. 128x128 tile, BK=64, 4 waves (2x2).
// LDS dest linear (gload_lds), source slot pre-swizzled (slot ^= row&7), read swizzled
// with the same involution -> ds_read 16-way conflict eliminated (rule 21).
#define GBM 128
#define GBN 128
#define GBK 64

__global__ __launch_bounds__(256) void qkv_gemm_kernel(const unsigned short* __restrict__ xb,
                                                       const unsigned short* __restrict__ wt,
                                                       const float* __restrict__ bq,
                                                       const float* __restrict__ bk,
                                                       const float* __restrict__ bv,
                                                       unsigned short* __restrict__ qk,
                                                       unsigned short* __restrict__ vT) {
    __shared__ unsigned short Asm[GBM * GBK];   // 16 KB
    __shared__ unsigned short Bsm[GBN * GBK];   // 16 KB
    const int tid = threadIdx.x;
    // chunked XCD swizzle: 1152 blocks = 8 x 144 (bijective)
    const int swz = (blockIdx.x & 7) * 144 + (blockIdx.x >> 3);
    const int bm = swz / 18, bn = swz % 18;
    const int w = tid >> 6, l = tid & 63;
    const int wm = w >> 1, wn = w & 1;
    const int lr = l & 15, lk = l >> 4;

    f32x4 zero = {0.f, 0.f, 0.f, 0.f};
    f32x4 acc[4][4];
#pragma unroll
    for (int i = 0; i < 4; i++)
#pragma unroll
        for (int j = 0; j < 4; j++) acc[i][j] = zero;

    // staging: instr j covers rows j*8..j*8+7; lane: row j*8+(l>>3).
    // source slot pre-swizzled: slot ^= (row&7)  (16B slots within the 128B row chunk)
    const int sr8 = l >> 3;                       // row within 8-row group = row&7
    const int scolS = (((l & 7) ^ sr8) * 8);      // swizzled source col (elems)
    const unsigned short* aBase = xb + (size_t)(bm * GBM) * K_;
    const unsigned short* bBase = wt + (size_t)(bn * GBN) * K_;

    for (int k0 = 0; k0 < K_; k0 += GBK) {
        __syncthreads();
#pragma unroll
        for (int i = 0; i < 4; i++) {
            const int j = w * 4 + i;
            __builtin_amdgcn_global_load_lds(
                (glb_u32*)(aBase + (size_t)(j * 8 + sr8) * K_ + k0 + scolS),
                (lds_u32*)(&Asm[j * 8 * GBK]), 16, 0, 0);
        }
#pragma unroll
        for (int i = 0; i < 4; i++) {
            const int j = w * 4 + i;
            __builtin_amdgcn_global_load_lds(
                (glb_u32*)(bBase + (size_t)(j * 8 + sr8) * K_ + k0 + scolS),
                (lds_u32*)(&Bsm[j * 8 * GBK]), 16, 0, 0);
        }
        __syncthreads();   // drains vmcnt -> LDS valid

#pragma unroll
        for (int ks = 0; ks < 2; ks++) {
            short8 a[4], b[4];
#pragma unroll
            for (int mi = 0; mi < 4; mi++) {
                const int row = wm * 64 + mi * 16 + lr;
                const int slot = ((ks * 4 + lk) ^ (lr & 7)) * 8;
                a[mi] = *reinterpret_cast<const short8*>(&Asm[row * GBK + slot]);
            }
#pragma unroll
            for (int ni = 0; ni < 4; ni++) {
                const int row = wn * 64 + ni * 16 + lr;
                const int slot = ((ks * 4 + lk) ^ (lr & 7)) * 8;
                b[ni] = *reinterpret_cast<const short8*>(&Bsm[row * GBK + slot]);
            }
#pragma unroll
            for (int mi = 0; mi < 4; mi++)
#pragma unroll
                for (int ni = 0; ni < 4; ni++)
                    acc[mi][ni] = __builtin_amdgcn_mfma_f32_16x16x32_bf16(a[mi], b[ni], acc[mi][ni], 0, 0, 0);
        }
    }

    // epilogue. C/D: col = lane&15, row = (lane>>4)*4 + i
    if (bn < 12) {      // Q,K region -> qk[row][1536]; Q pre-scaled by 0.125*log2e
#pragma unroll
        for (int ni = 0; ni < 4; ni++) {
            const int col = bn * GBN + wn * 64 + ni * 16 + lr;
            const bool isQ = (col < H_);
            const float bias = isQ ? bq[col] : bk[col - H_];
            const float scl = isQ ? (0.125f * LOG2E) : 1.0f;
#pragma unroll
            for (int mi = 0; mi < 4; mi++) {
#pragma unroll
                for (int i = 0; i < 4; i++) {
                    const int row = bm * GBM + wm * 64 + mi * 16 + lk * 4 + i;
                    qk[(size_t)row * NQK + col] = f2bf((acc[mi][ni][i] + bias) * scl);
                }
            }
        }
    } else {            // V region -> vT[(b*12+h)*64+d][s], 4 consecutive s packed
#pragma unroll
        for (int ni = 0; ni < 4; ni++) {
            const int c = bn * GBN - 2 * H_ + wn * 64 + ni * 16 + lr;  // 0..767
            const int h = c >> 6, d = c & 63;
            const float bias = bv[c];
#pragma unroll
            for (int mi = 0; mi < 4; mi++) {
                const int row0 = bm * GBM + wm * 64 + mi * 16 + lk * 4;
                const int b = row0 >> 12, s0 = row0 & (S_ - 1);
                union { unsigned short s[4]; ushort4v v; } u;
#pragma unroll
                for (int i = 0; i < 4; i++) u.s[i] = f2bf(acc[mi][ni][i] + bias);
                *reinterpret_cast<ushort4v*>(vT + ((size_t)(b * NH_ + h) * DH_ + d) * S_ + s0) = u.v;
            }
        }
    }
}

// ---------------- flash attention fwd + tanh ----------------
// 4 waves x 32 q-rows (QB=128), KB=64, 32x32x16 MFMA, swapped QK^T, in-register
// softmax. VALU cuts: C-init = -m_ (no subs), max3-shaped pmax tree, T12/T13/T14.
#define QW 32
#define QB 128
#define KB 64

__global__ __launch_bounds__(256, 2) void attn_kernel(const unsigned short* __restrict__ qk,
                                                      const unsigned short* __restrict__ vT,
                                                      float* __restrict__ out) {
    __shared__ unsigned short Ksm[KB * 64];
    __shared__ unsigned short Vsm[DH_ * KB];
    const int tid = threadIdx.x;
    const int w = tid >> 6, l = tid & 63;
    const int ln = l & 31, hi = l >> 5;
    // XCD-chunked swizzle: 768 blocks = 8 XCD x 96
    const int swz = (blockIdx.x & 7) * 96 + (blockIdx.x >> 3);
    const int qt = swz & 31, bh = swz >> 5;
    const int b = bh / NH_, h = bh % NH_;

    const unsigned short* Qg = qk + (size_t)b * S_ * NQK + h * DH_;
    const unsigned short* Kg = Qg + H_;
    const unsigned short* Vg = vT + (size_t)bh * DH_ * S_;

    // Q fragments in regs (B operand of swapped QK^T: lane ln = q row)
    const int qrow = qt * QB + w * QW + ln;
    short8 qf[4];
    {
        const unsigned short* qp = Qg + (size_t)qrow * NQK + hi * 8;
#pragma unroll
        for (int dk = 0; dk < 4; dk++)
            qf[dk] = *reinterpret_cast<const short8*>(qp + dk * 16);
    }

    const f32x16 fz = {0,0,0,0,0,0,0,0,0,0,0,0,0,0,0,0};
    f32x16 o0 = fz, o1 = fz;
    float m_ = 0.f, lsum = 0.f;   // m_ = running max in exp2 domain (scores tiny; 0-start safe)

    // staging: thread -> (row = tid>>2, 16 elems at (tid&3)*16); 2x 16B each of K,V^T
    const int srow = tid >> 2;
    const int sd = (tid & 3) * 16;
    const unsigned short* kgp = Kg + (size_t)srow * NQK + sd;
    const unsigned short* vgp = Vg + (size_t)srow * S_ + sd;
    const int sidx0 = (srow * 64 + sd) ^ ((srow & 7) << 3);
    const int sidx1 = (srow * 64 + sd + 8) ^ ((srow & 7) << 3);

    // T14: issue tile-0 loads before the loop
    uint4v kr0 = *reinterpret_cast<const uint4v*>(kgp);
    uint4v kr1 = *reinterpret_cast<const uint4v*>(kgp + 8);
    uint4v vr0 = *reinterpret_cast<const uint4v*>(vgp);
    uint4v vr1 = *reinterpret_cast<const uint4v*>(vgp + 8);

    for (int kt = 0; kt < S_; kt += KB) {
        // barrier 1: previous tile's readers done (no vmcnt drain)
        asm volatile("" ::: "memory");
        __builtin_amdgcn_s_barrier();
        asm volatile("" ::: "memory");
        *reinterpret_cast<uint4v*>(&Ksm[sidx0]) = kr0;
        *reinterpret_cast<uint4v*>(&Ksm[sidx1]) = kr1;
        *reinterpret_cast<uint4v*>(&Vsm[sidx0]) = vr0;
        *reinterpret_cast<uint4v*>(&Vsm[sidx1]) = vr1;
        if (kt + KB < S_) {    // issue next-tile loads; they fly during compute
            kr0 = *reinterpret_cast<const uint4v*>(kgp + (size_t)(kt + KB) * NQK);
            kr1 = *reinterpret_cast<const uint4v*>(kgp + (size_t)(kt + KB) * NQK + 8);
            vr0 = *reinterpret_cast<const uint4v*>(vgp + kt + KB);
            vr1 = *reinterpret_cast<const uint4v*>(vgp + kt + KB + 8);
        }
        // barrier 2: LDS writes visible (lgkm only, vmcnt stays in flight)
        asm volatile("s_waitcnt lgkmcnt(0)" ::: "memory");
        __builtin_amdgcn_s_barrier();
        asm volatile("" ::: "memory");

        // S' = K Q^T - m_  (C-init trick: accumulator seeded with -m_; Q pre-scaled)
        f32x16 cm;
#pragma unroll
        for (int r = 0; r < 16; r++) cm[r] = -m_;
        f32x16 s0 = cm, s1 = cm;
#pragma unroll
        for (int dk = 0; dk < 4; dk++) {
            const int col = dk * 16 + hi * 8;
            short8 kf0 = *reinterpret_cast<const short8*>(&Ksm[(ln * 64 + col) ^ ((ln & 7) << 3)]);
            short8 kf1 = *reinterpret_cast<const short8*>(&Ksm[((32 + ln) * 64 + col) ^ ((ln & 7) << 3)]);
            s0 = __builtin_amdgcn_mfma_f32_32x32x16_bf16(kf0, qf[dk], s0, 0, 0, 0);
            s1 = __builtin_amdgcn_mfma_f32_32x32x16_bf16(kf1, qf[dk], s1, 0, 0, 0);
        }

        // ---- pmax via max3-shaped tree; defer-max (THR=8, exp2 domain) ----
        float pm = -1e30f;
#pragma unroll
        for (int r = 0; r < 16; r += 4)
            pm = fmaxf(fmaxf(pm, s0[r]), fmaxf(fmaxf(s0[r+1], s0[r+2]), s0[r+3]));
#pragma unroll
        for (int r = 0; r < 16; r += 4)
            pm = fmaxf(fmaxf(pm, s1[r]), fmaxf(fmaxf(s1[r+1], s1[r+2]), s1[r+3]));
        pm = fmaxf(pm, __shfl_xor(pm, 32));
        if (!__all(pm <= 8.0f)) {     // rare rescale path
            const float step = fmaxf(pm, 0.f);
            const float corr = exp2_fast(-step);
            m_ += step;
            lsum *= corr;
#pragma unroll
            for (int r = 0; r < 16; r++) { s0[r] -= step; s1[r] -= step; }
#pragma unroll
            for (int r = 0; r < 16; r++) {
                const float c = __shfl(corr, (r & 3) + 8 * (r >> 2) + 4 * hi);
                o0[r] *= c; o1[r] *= c;
            }
        }
        float p[32];
        float rs = 0.f;
#pragma unroll
        for (int r = 0; r < 16; r++) { p[r] = exp2_fast(s0[r]); rs += p[r]; }
#pragma unroll
        for (int r = 0; r < 16; r++) { p[16 + r] = exp2_fast(s1[r]); rs += p[16 + r]; }
        rs += __shfl_xor(rs, 32);
        lsum += rs;

        // ---- P -> bf16 A-frags (T12: cvt_pk + permlane32_swap) ----
        short8 pa[4];
#pragma unroll
        for (int half = 0; half < 2; half++) {
            unsigned int c0 = cvtpk_bf16(p[half*16+0],  p[half*16+1]);
            unsigned int c1 = cvtpk_bf16(p[half*16+2],  p[half*16+3]);
            unsigned int c2 = cvtpk_bf16(p[half*16+4],  p[half*16+5]);
            unsigned int c3 = cvtpk_bf16(p[half*16+6],  p[half*16+7]);
            unsigned int c4 = cvtpk_bf16(p[half*16+8],  p[half*16+9]);
            unsigned int c5 = cvtpk_bf16(p[half*16+10], p[half*16+11]);
            unsigned int c6 = cvtpk_bf16(p[half*16+12], p[half*16+13]);
            unsigned int c7 = cvtpk_bf16(p[half*16+14], p[half*16+15]);
            plswap32(c0, c2); plswap32(c1, c3);
            plswap32(c4, c6); plswap32(c5, c7);
            union { unsigned int u[4]; short8 v; } ua, ub;
            ua.u[0] = c0; ua.u[1] = c1; ua.u[2] = c2; ua.u[3] = c3;
            ub.u[0] = c4; ub.u[1] = c5; ub.u[2] = c6; ub.u[3] = c7;
            pa[half * 2]     = ua.v;
            pa[half * 2 + 1] = ub.v;
        }

        // ---- O += P V : A=pa (m=q), B=V^T rows (n=d) ----
#pragma unroll
        for (int s4 = 0; s4 < 4; s4++) {
            const int kcol = s4 * 16 + hi * 8;
            short8 vf0 = *reinterpret_cast<const short8*>(&Vsm[(ln * 64 + kcol) ^ ((ln & 7) << 3)]);
            short8 vf1 = *reinterpret_cast<const short8*>(&Vsm[((32 + ln) * 64 + kcol) ^ ((ln & 7) << 3)]);
            o0 = __builtin_amdgcn_mfma_f32_32x32x16_bf16(pa[s4], vf0, o0, 0, 0, 0);
            o1 = __builtin_amdgcn_mfma_f32_32x32x16_bf16(pa[s4], vf1, o1, 0, 0, 0);
        }
    }

    // epilogue: O[q=crow(r,hi)][d=dt*32+ln], normalize, tanh, fp32 store
    float* op = out + ((size_t)b * S_ + qt * QB + w * QW) * H_ + h * DH_;
#pragma unroll
    for (int r = 0; r < 16; r++) {
        const int q = (r & 3) + 8 * (r >> 2) + 4 * hi;
        const float inv = 1.0f / __shfl(lsum, q);
        op[(size_t)q * H_ + ln]      = tanhf(o0[r] * inv);
        op[(size_t)q * H_ + 32 + ln] = tanhf(o1[r] * inv);
    }
}

extern "C" void kernel_launch(void* const* d_in, const int* in_sizes, int n_in,
                              void* d_out, int out_size, void* d_ws, size_t ws_size,
                              hipStream_t stream) {
    const float* x  = (const float*)d_in[0];
    const float* Wq = (const float*)d_in[1];
    const float* bq = (const float*)d_in[2];
    const float* Wk = (const float*)d_in[3];
    const float* bk = (const float*)d_in[4];
    const float* Wv = (const float*)d_in[5];
    const float* bv = (const float*)d_in[6];
    float* out = (float*)d_out;

    // ws (bytes): xb 12.58MB | wt 3.54MB | qk 25.17MB | vT 12.58MB = 53.87MB
    char* ws = (char*)d_ws;
    unsigned short* xb = (unsigned short*)ws;
    size_t off = (size_t)M_ * K_ * 2;
    unsigned short* wt = (unsigned short*)(ws + off);
    off += (size_t)N3_ * K_ * 2;
    unsigned short* qkb = (unsigned short*)(ws + off);
    off += (size_t)M_ * NQK * 2;
    unsigned short* vTb = (unsigned short*)(ws + off);

    cast_x_kernel<<<dim3((M_ * K_) / 4 / 256), dim3(256), 0, stream>>>(x, xb);
    cast_w_kernel<<<dim3((3 * H_ * 96) / 256), dim3(256), 0, stream>>>(Wq, Wk, Wv, wt);
    qkv_gemm_kernel<<<dim3((M_ / GBM) * (N3_ / GBN)), dim3(256), 0, stream>>>(xb, wt, bq, bk, bv, qkb, vTb);
    attn_kernel<<<dim3(B_ * NH_ * (S_ / QB)), dim3(256), 0, stream>>>(qkb, vTb, out);
}

// Round 7
// 266.576 us; speedup vs baseline: 2.0213x; 1.0160x over previous
//
#include <hip/hip_runtime.h>
#include <hip/hip_bf16.h>

// B=2, S=4096, H=768, NH=12, DH=64. fp32 in/out, bf16 MFMA compute.
#define B_ 2
#define S_ 4096
#define H_ 768
#define NH_ 12
#define DH_ 64
#define M_ (B_ * S_)    // 8192
#define N3_ (3 * H_)    // 2304
#define NQK 1536        // Q,K interleaved row width
#define K_ H_
#define LOG2E 1.4426950408889634f

typedef __attribute__((ext_vector_type(8))) short short8;     // 8 bf16 (4 VGPR)
typedef __attribute__((ext_vector_type(4))) float f32x4;
typedef __attribute__((ext_vector_type(16))) float f32x16;
typedef __attribute__((ext_vector_type(4))) unsigned int uint4v;
typedef __attribute__((ext_vector_type(4))) unsigned short ushort4v;

typedef __attribute__((address_space(3))) unsigned int lds_u32;
typedef const __attribute__((address_space(1))) unsigned int glb_u32;

__device__ __forceinline__ unsigned short f2bf(float f) {
    unsigned int u = __builtin_bit_cast(unsigned int, f);
    u += 0x7FFFu + ((u >> 16) & 1u);   // RNE
    return (unsigned short)(u >> 16);
}
__device__ __forceinline__ unsigned int cvtpk_bf16(float lo, float hi) {
    unsigned int r;
    asm("v_cvt_pk_bf16_f32 %0, %1, %2" : "=v"(r) : "v"(lo), "v"(hi));
    return r;
}
// post: x.hi32lanes <- y.lo32lanes(lane^32), y.lo32lanes <- x.hi32lanes(lane^32)
__device__ __forceinline__ void plswap32(unsigned int &x, unsigned int &y) {
    asm("v_permlane32_swap_b32 %0, %1" : "+v"(x), "+v"(y));
}
__device__ __forceinline__ float exp2_fast(float x) {   // v_exp_f32: D = 2^S0
    float r;
    asm("v_exp_f32 %0, %1" : "=v"(r) : "v"(x));
    return r;
}

// ---------------- cast x: fp32 -> bf16, vectorized ----------------
__global__ __launch_bounds__(256) void cast_x_kernel(const float* __restrict__ x,
                                                     unsigned short* __restrict__ xb) {
    int i = blockIdx.x * 256 + threadIdx.x;   // exact grid: n/4 threads
    float4 v = reinterpret_cast<const float4*>(x)[i];
    ushort4 o;
    o.x = f2bf(v.x); o.y = f2bf(v.y); o.z = f2bf(v.z); o.w = f2bf(v.w);
    reinterpret_cast<ushort4*>(xb)[i] = o;
}

// ------- cast+transpose W: wt[(wsel*768+n)*768+k] = W[k*768+n] -------
__global__ __launch_bounds__(256) void cast_w_kernel(const float* __restrict__ Wq,
                                                     const float* __restrict__ Wk,
                                                     const float* __restrict__ Wv,
                                                     unsigned short* __restrict__ wt) {
    int id = blockIdx.x * 256 + threadIdx.x;   // 3*768*96 threads
    int n = id % H_;
    int kb = (id / H_) % 96;
    int wsel = id / (H_ * 96);
    const float* W = (wsel == 0) ? Wq : (wsel == 1) ? Wk : Wv;
    union { unsigned short s[8]; uint4v v; } u;
#pragma unroll
    for (int j = 0; j < 8; j++) u.s[j] = f2bf(W[(size_t)(kb * 8 + j) * H_ + n]);
    *reinterpret_cast<uint4v*>(wt + (size_t)(wsel * H_ + n) * H_ + kb * 8) = u.v;
}

// ---------------- fused QKV GEMM: 2-phase double-buffered (T3-min) ----------------
// [8192x768]bf16 @ [768x2304]bf16 + bias. 128x128 tile, BK=64, 4 waves (2x2).
// Per K-step: issue next tile's global_load_lds into buf^1 FIRST, then ds_read+MFMA
// on buf, then ONE vmcnt(0)+barrier. Staging latency hides under 32 MFMAs.
// LDS dest linear (gload_lds requirement); source slot pre-swizzled (slot ^= row&7),
// frag-read applies the same involution (rule 21).
#define GBM 128
#define GBN 128
#define GBK 64
#define NT (K_ / GBK)   // 12

__global__ __launch_bounds__(256) void qkv_gemm_kernel(const unsigned short* __restrict__ xb,
                                                       const unsigned short* __restrict__ wt,
                                                       const float* __restrict__ bq,
                                                       const float* __restrict__ bk,
                                                       const float* __restrict__ bv,
                                                       unsigned short* __restrict__ qk,
                                                       unsigned short* __restrict__ vT) {
    __shared__ unsigned short Asm[2][GBM * GBK];   // 2 x 16 KB
    __shared__ unsigned short Bsm[2][GBN * GBK];   // 2 x 16 KB
    const int tid = threadIdx.x;
    // chunked XCD swizzle: 1152 blocks = 8 x 144 (bijective)
    const int swz = (blockIdx.x & 7) * 144 + (blockIdx.x >> 3);
    const int bm = swz / 18, bn = swz % 18;
    const int w = tid >> 6, l = tid & 63;
    const int wm = w >> 1, wn = w & 1;
    const int lr = l & 15, lk = l >> 4;

    f32x4 zero = {0.f, 0.f, 0.f, 0.f};
    f32x4 acc[4][4];
#pragma unroll
    for (int i = 0; i < 4; i++)
#pragma unroll
        for (int j = 0; j < 4; j++) acc[i][j] = zero;

    // staging: instr j covers rows j*8..j*8+7; lane: row j*8+(l>>3), 16B slot (l&7)^row&7
    const int sr8 = l >> 3;
    const int scolS = ((l & 7) ^ sr8) * 8;
    const unsigned short* aSrc = xb + (size_t)(bm * GBM + sr8) * K_ + scolS;
    const unsigned short* bSrc = wt + (size_t)(bn * GBN + sr8) * K_ + scolS;

#define STAGE(buf, k0)                                                             \
    do {                                                                           \
        _Pragma("unroll")                                                          \
        for (int i_ = 0; i_ < 4; i_++) {                                           \
            const int j_ = w * 4 + i_;                                             \
            __builtin_amdgcn_global_load_lds(                                      \
                (glb_u32*)(aSrc + (size_t)j_ * 8 * K_ + (k0)),                     \
                (lds_u32*)(&Asm[buf][j_ * 8 * GBK]), 16, 0, 0);                    \
        }                                                                          \
        _Pragma("unroll")                                                          \
        for (int i_ = 0; i_ < 4; i_++) {                                           \
            const int j_ = w * 4 + i_;                                             \
            __builtin_amdgcn_global_load_lds(                                      \
                (glb_u32*)(bSrc + (size_t)j_ * 8 * K_ + (k0)),                     \
                (lds_u32*)(&Bsm[buf][j_ * 8 * GBK]), 16, 0, 0);                    \
        }                                                                          \
    } while (0)

    // prologue: stage tile 0 and wait for it
    STAGE(0, 0);
    asm volatile("s_waitcnt vmcnt(0)" ::: "memory");
    __builtin_amdgcn_s_barrier();
    asm volatile("" ::: "memory");

#pragma unroll
    for (int t = 0; t < NT; ++t) {
        const int cur = t & 1;
        if (t + 1 < NT) STAGE(cur ^ 1, (t + 1) * GBK);   // issue BEFORE compute

#pragma unroll
        for (int ks = 0; ks < 2; ks++) {
            short8 a[4], b[4];
#pragma unroll
            for (int mi = 0; mi < 4; mi++) {
                const int row = wm * 64 + mi * 16 + lr;
                const int slot = ((ks * 4 + lk) ^ (lr & 7)) * 8;
                a[mi] = *reinterpret_cast<const short8*>(&Asm[cur][row * GBK + slot]);
            }
#pragma unroll
            for (int ni = 0; ni < 4; ni++) {
                const int row = wn * 64 + ni * 16 + lr;
                const int slot = ((ks * 4 + lk) ^ (lr & 7)) * 8;
                b[ni] = *reinterpret_cast<const short8*>(&Bsm[cur][row * GBK + slot]);
            }
#pragma unroll
            for (int mi = 0; mi < 4; mi++)
#pragma unroll
                for (int ni = 0; ni < 4; ni++)
                    acc[mi][ni] = __builtin_amdgcn_mfma_f32_16x16x32_bf16(a[mi], b[ni], acc[mi][ni], 0, 0, 0);
        }

        if (t + 1 < NT) {   // one drain+barrier per K-step: next buf staged, cur free
            asm volatile("s_waitcnt vmcnt(0)" ::: "memory");
            __builtin_amdgcn_s_barrier();
            asm volatile("" ::: "memory");
        }
    }
#undef STAGE

    // epilogue. C/D: col = lane&15, row = (lane>>4)*4 + i
    if (bn < 12) {      // Q,K region -> qk[row][1536]; Q pre-scaled by 0.125*log2e
#pragma unroll
        for (int ni = 0; ni < 4; ni++) {
            const int col = bn * GBN + wn * 64 + ni * 16 + lr;
            const bool isQ = (col < H_);
            const float bias = isQ ? bq[col] : bk[col - H_];
            const float scl = isQ ? (0.125f * LOG2E) : 1.0f;
#pragma unroll
            for (int mi = 0; mi < 4; mi++) {
#pragma unroll
                for (int i = 0; i < 4; i++) {
                    const int row = bm * GBM + wm * 64 + mi * 16 + lk * 4 + i;
                    qk[(size_t)row * NQK + col] = f2bf((acc[mi][ni][i] + bias) * scl);
                }
            }
        }
    } else {            // V region -> vT[(b*12+h)*64+d][s], 4 consecutive s packed
#pragma unroll
        for (int ni = 0; ni < 4; ni++) {
            const int c = bn * GBN - 2 * H_ + wn * 64 + ni * 16 + lr;  // 0..767
            const int h = c >> 6, d = c & 63;
            const float bias = bv[c];
#pragma unroll
            for (int mi = 0; mi < 4; mi++) {
                const int row0 = bm * GBM + wm * 64 + mi * 16 + lk * 4;
                const int b = row0 >> 12, s0 = row0 & (S_ - 1);
                union { unsigned short s[4]; ushort4v v; } u;
#pragma unroll
                for (int i = 0; i < 4; i++) u.s[i] = f2bf(acc[mi][ni][i] + bias);
                *reinterpret_cast<ushort4v*>(vT + ((size_t)(b * NH_ + h) * DH_ + d) * S_ + s0) = u.v;
            }
        }
    }
}

// ---------------- flash attention fwd + tanh (unchanged from R6) ----------------
#define QW 32
#define QB 128
#define KB 64

__global__ __launch_bounds__(256, 2) void attn_kernel(const unsigned short* __restrict__ qk,
                                                      const unsigned short* __restrict__ vT,
                                                      float* __restrict__ out) {
    __shared__ unsigned short Ksm[KB * 64];
    __shared__ unsigned short Vsm[DH_ * KB];
    const int tid = threadIdx.x;
    const int w = tid >> 6, l = tid & 63;
    const int ln = l & 31, hi = l >> 5;
    // XCD-chunked swizzle: 768 blocks = 8 XCD x 96
    const int swz = (blockIdx.x & 7) * 96 + (blockIdx.x >> 3);
    const int qt = swz & 31, bh = swz >> 5;
    const int b = bh / NH_, h = bh % NH_;

    const unsigned short* Qg = qk + (size_t)b * S_ * NQK + h * DH_;
    const unsigned short* Kg = Qg + H_;
    const unsigned short* Vg = vT + (size_t)bh * DH_ * S_;

    // Q fragments in regs (B operand of swapped QK^T: lane ln = q row)
    const int qrow = qt * QB + w * QW + ln;
    short8 qf[4];
    {
        const unsigned short* qp = Qg + (size_t)qrow * NQK + hi * 8;
#pragma unroll
        for (int dk = 0; dk < 4; dk++)
            qf[dk] = *reinterpret_cast<const short8*>(qp + dk * 16);
    }

    const f32x16 fz = {0,0,0,0,0,0,0,0,0,0,0,0,0,0,0,0};
    f32x16 o0 = fz, o1 = fz;
    float m_ = 0.f, lsum = 0.f;   // running max in exp2 domain (scores tiny; 0-start safe)

    // staging: thread -> (row = tid>>2, 16 elems at (tid&3)*16); 2x 16B each of K,V^T
    const int srow = tid >> 2;
    const int sd = (tid & 3) * 16;
    const unsigned short* kgp = Kg + (size_t)srow * NQK + sd;
    const unsigned short* vgp = Vg + (size_t)srow * S_ + sd;
    const int sidx0 = (srow * 64 + sd) ^ ((srow & 7) << 3);
    const int sidx1 = (srow * 64 + sd + 8) ^ ((srow & 7) << 3);

    // T14: issue tile-0 loads before the loop
    uint4v kr0 = *reinterpret_cast<const uint4v*>(kgp);
    uint4v kr1 = *reinterpret_cast<const uint4v*>(kgp + 8);
    uint4v vr0 = *reinterpret_cast<const uint4v*>(vgp);
    uint4v vr1 = *reinterpret_cast<const uint4v*>(vgp + 8);

    for (int kt = 0; kt < S_; kt += KB) {
        // barrier 1: previous tile's readers done (no vmcnt drain)
        asm volatile("" ::: "memory");
        __builtin_amdgcn_s_barrier();
        asm volatile("" ::: "memory");
        *reinterpret_cast<uint4v*>(&Ksm[sidx0]) = kr0;
        *reinterpret_cast<uint4v*>(&Ksm[sidx1]) = kr1;
        *reinterpret_cast<uint4v*>(&Vsm[sidx0]) = vr0;
        *reinterpret_cast<uint4v*>(&Vsm[sidx1]) = vr1;
        if (kt + KB < S_) {    // issue next-tile loads; they fly during compute
            kr0 = *reinterpret_cast<const uint4v*>(kgp + (size_t)(kt + KB) * NQK);
            kr1 = *reinterpret_cast<const uint4v*>(kgp + (size_t)(kt + KB) * NQK + 8);
            vr0 = *reinterpret_cast<const uint4v*>(vgp + kt + KB);
            vr1 = *reinterpret_cast<const uint4v*>(vgp + kt + KB + 8);
        }
        // barrier 2: LDS writes visible (lgkm only, vmcnt stays in flight)
        asm volatile("s_waitcnt lgkmcnt(0)" ::: "memory");
        __builtin_amdgcn_s_barrier();
        asm volatile("" ::: "memory");

        // S' = K Q^T - m_  (C-init trick: accumulator seeded with -m_; Q pre-scaled)
        f32x16 cm;
#pragma unroll
        for (int r = 0; r < 16; r++) cm[r] = -m_;
        f32x16 s0 = cm, s1 = cm;
#pragma unroll
        for (int dk = 0; dk < 4; dk++) {
            const int col = dk * 16 + hi * 8;
            short8 kf0 = *reinterpret_cast<const short8*>(&Ksm[(ln * 64 + col) ^ ((ln & 7) << 3)]);
            short8 kf1 = *reinterpret_cast<const short8*>(&Ksm[((32 + ln) * 64 + col) ^ ((ln & 7) << 3)]);
            s0 = __builtin_amdgcn_mfma_f32_32x32x16_bf16(kf0, qf[dk], s0, 0, 0, 0);
            s1 = __builtin_amdgcn_mfma_f32_32x32x16_bf16(kf1, qf[dk], s1, 0, 0, 0);
        }

        // ---- pmax via max3-shaped tree; defer-max (THR=8, exp2 domain) ----
        float pm = -1e30f;
#pragma unroll
        for (int r = 0; r < 16; r += 4)
            pm = fmaxf(fmaxf(pm, s0[r]), fmaxf(fmaxf(s0[r+1], s0[r+2]), s0[r+3]));
#pragma unroll
        for (int r = 0; r < 16; r += 4)
            pm = fmaxf(fmaxf(pm, s1[r]), fmaxf(fmaxf(s1[r+1], s1[r+2]), s1[r+3]));
        pm = fmaxf(pm, __shfl_xor(pm, 32));
        if (!__all(pm <= 8.0f)) {     // rare rescale path
            const float step = fmaxf(pm, 0.f);
            const float corr = exp2_fast(-step);
            m_ += step;
            lsum *= corr;
#pragma unroll
            for (int r = 0; r < 16; r++) { s0[r] -= step; s1[r] -= step; }
#pragma unroll
            for (int r = 0; r < 16; r++) {
                const float c = __shfl(corr, (r & 3) + 8 * (r >> 2) + 4 * hi);
                o0[r] *= c; o1[r] *= c;
            }
        }
        float p[32];
        float rs = 0.f;
#pragma unroll
        for (int r = 0; r < 16; r++) { p[r] = exp2_fast(s0[r]); rs += p[r]; }
#pragma unroll
        for (int r = 0; r < 16; r++) { p[16 + r] = exp2_fast(s1[r]); rs += p[16 + r]; }
        rs += __shfl_xor(rs, 32);
        lsum += rs;

        // ---- P -> bf16 A-frags (T12: cvt_pk + permlane32_swap) ----
        short8 pa[4];
#pragma unroll
        for (int half = 0; half < 2; half++) {
            unsigned int c0 = cvtpk_bf16(p[half*16+0],  p[half*16+1]);
            unsigned int c1 = cvtpk_bf16(p[half*16+2],  p[half*16+3]);
            unsigned int c2 = cvtpk_bf16(p[half*16+4],  p[half*16+5]);
            unsigned int c3 = cvtpk_bf16(p[half*16+6],  p[half*16+7]);
            unsigned int c4 = cvtpk_bf16(p[half*16+8],  p[half*16+9]);
            unsigned int c5 = cvtpk_bf16(p[half*16+10], p[half*16+11]);
            unsigned int c6 = cvtpk_bf16(p[half*16+12], p[half*16+13]);
            unsigned int c7 = cvtpk_bf16(p[half*16+14], p[half*16+15]);
            plswap32(c0, c2); plswap32(c1, c3);
            plswap32(c4, c6); plswap32(c5, c7);
            union { unsigned int u[4]; short8 v; } ua, ub;
            ua.u[0] = c0; ua.u[1] = c1; ua.u[2] = c2; ua.u[3] = c3;
            ub.u[0] = c4; ub.u[1] = c5; ub.u[2] = c6; ub.u[3] = c7;
            pa[half * 2]     = ua.v;
            pa[half * 2 + 1] = ub.v;
        }

        // ---- O += P V : A=pa (m=q), B=V^T rows (n=d) ----
#pragma unroll
        for (int s4 = 0; s4 < 4; s4++) {
            const int kcol = s4 * 16 + hi * 8;
            short8 vf0 = *reinterpret_cast<const short8*>(&Vsm[(ln * 64 + kcol) ^ ((ln & 7) << 3)]);
            short8 vf1 = *reinterpret_cast<const short8*>(&Vsm[((32 + ln) * 64 + kcol) ^ ((ln & 7) << 3)]);
            o0 = __builtin_amdgcn_mfma_f32_32x32x16_bf16(pa[s4], vf0, o0, 0, 0, 0);
            o1 = __builtin_amdgcn_mfma_f32_32x32x16_bf16(pa[s4], vf1, o1, 0, 0, 0);
        }
    }

    // epilogue: O[q=crow(r,hi)][d=dt*32+ln], normalize, tanh, fp32 store
    float* op = out + ((size_t)b * S_ + qt * QB + w * QW) * H_ + h * DH_;
#pragma unroll
    for (int r = 0; r < 16; r++) {
        const int q = (r & 3) + 8 * (r >> 2) + 4 * hi;
        const float inv = 1.0f / __shfl(lsum, q);
        op[(size_t)q * H_ + ln]      = tanhf(o0[r] * inv);
        op[(size_t)q * H_ + 32 + ln] = tanhf(o1[r] * inv);
    }
}

extern "C" void kernel_launch(void* const* d_in, const int* in_sizes, int n_in,
                              void* d_out, int out_size, void* d_ws, size_t ws_size,
                              hipStream_t stream) {
    const float* x  = (const float*)d_in[0];
    const float* Wq = (const float*)d_in[1];
    const float* bq = (const float*)d_in[2];
    const float* Wk = (const float*)d_in[3];
    const float* bk = (const float*)d_in[4];
    const float* Wv = (const float*)d_in[5];
    const float* bv = (const float*)d_in[6];
    float* out = (float*)d_out;

    // ws (bytes): xb 12.58MB | wt 3.54MB | qk 25.17MB | vT 12.58MB = 53.87MB
    char* ws = (char*)d_ws;
    unsigned short* xb = (unsigned short*)ws;
    size_t off = (size_t)M_ * K_ * 2;
    unsigned short* wt = (unsigned short*)(ws + off);
    off += (size_t)N3_ * K_ * 2;
    unsigned short* qkb = (unsigned short*)(ws + off);
    off += (size_t)M_ * NQK * 2;
    unsigned short* vTb = (unsigned short*)(ws + off);

    cast_x_kernel<<<dim3((M_ * K_) / 4 / 256), dim3(256), 0, stream>>>(x, xb);
    cast_w_kernel<<<dim3((3 * H_ * 96) / 256), dim3(256), 0, stream>>>(Wq, Wk, Wv, wt);
    qkv_gemm_kernel<<<dim3((M_ / GBM) * (N3_ / GBN)), dim3(256), 0, stream>>>(xb, wt, bq, bk, bv, qkb, vTb);
    attn_kernel<<<dim3(B_ * NH_ * (S_ / QB)), dim3(256), 0, stream>>>(qkb, vTb, out);
}